// Round 9
// baseline (114.286 us; speedup 1.0000x reference)
//
#include <hip/hip_runtime.h>
#include <hip/hip_bf16.h>

constexpr int T   = 16384;  // tokens
constexpr int HD  = 4096;   // hidden dim
constexpr int E   = 64;     // experts
constexpr int BKC = 32;     // k per chunk
constexpr int CPW = 32;     // chunks per wave (K-quarter = 32*32 = 1024)

using short8 = __attribute__((ext_vector_type(8))) short;
using f32x4  = __attribute__((ext_vector_type(4))) float;

__device__ __forceinline__ unsigned short f2bf(float x) {
  union { float f; unsigned u; } v; v.f = x;
  return (unsigned short)((v.u + 0x7FFFu + ((v.u >> 16) & 1u)) >> 16);
}
__device__ __forceinline__ float bf2f(unsigned short h) {
  union { float f; unsigned u; } v; v.u = ((unsigned)h) << 16;
  return v.f;
}

// ---------------------------------------------------------------------------
// Kernel 0: pack W (fp32 [64][4096]) into bf16 hi/lo image:
// img[chunk 128][expert 64][slot 8] x 16B; slot 0..3 = hi k-group (8 bf16 of
// k [8s..8s+8)), slot 4..7 = lo residual of group s-4.
// ---------------------------------------------------------------------------
__global__ __launch_bounds__(256) void wprep(const float* __restrict__ W,
                                             short* __restrict__ img) {
  const int tid = blockIdx.x * 256 + threadIdx.x;   // 0..65535
  const int c   = tid >> 9;
  const int rem = tid & 511;
  const int e   = rem >> 3;
  const int sp  = rem & 7;
  const int part = sp >> 2;   // 0 = hi, 1 = lo
  const int sl   = sp & 3;    // k-group
  const float* src = W + (size_t)e * HD + c * BKC + sl * 8;
  short8 v;
#pragma unroll
  for (int j = 0; j < 8; ++j) {
    float x = src[j];
    unsigned short h = f2bf(x);
    v[j] = part ? (short)f2bf(x - bf2f(h)) : (short)h;
  }
  *(short8*)(img + (size_t)tid * 8) = v;
}

// ---------------------------------------------------------------------------
// Kernel 1: fused router — barrier-free, LDS-free main loop.
// 512 blocks x 256 threads (4 waves) = 2 blocks/CU, 8 waves/CU, 2 waves/SIMD.
// Block owns 32 token rows; wave w owns the K-quarter [1024w, 1024w+1024)
// as 32 chunks of BK=32, computing 32 rows x 64 experts partial logits.
// A: global->VGPR depth-4 prefetch (3-body in-order slack > HBM latency).
// B: global->VGPR depth-1 from the L2-resident 1 MiB image (1-body slack).
// Loop fully unrolled: every array index compile-time (rule #20), no asm
// waits — compiler places minimal per-dependency vmcnt.
// Epilogue: LDS reduction across 4 K-quarters + logits write + fused top-2.
// ---------------------------------------------------------------------------
__global__ __launch_bounds__(256, 2) void router_fused(
    const float* __restrict__ H, const short* __restrict__ img,
    float* __restrict__ logits, float* __restrict__ topw, float* __restrict__ topi) {
  __shared__ __align__(16) float part[4][32][64];   // 32 KB

  const int tid  = threadIdx.x;
  const int w    = tid >> 6;    // wave = K-quarter
  const int lane = tid & 63;
  const int q    = lane >> 4;   // k-group / C row-group
  const int r    = lane & 15;   // A row / B expert sub-index
  const int row0 = blockIdx.x * 32;

  // A bases: frag f covers rows row0+16f+r; wave's K-base = w*1024 floats
  const float* pA0 = H + (size_t)(row0 + r) * HD + w * 1024 + q * 8;
  const float* pA1 = pA0 + (size_t)16 * HD;
  // B base: global chunk c = w*CPW + t; lane offset r*64 + q*8 shorts
  const short* pB = img + (size_t)(w * CPW) * 4096 + r * 64 + q * 8;

  f32x4  Ab[4][2][2];         // [slot t&3][frag][half]
  short8 Bh[2][4], Bl[2][4];  // [slot t&1][ct]
  f32x4  acc[2][4];
#pragma unroll
  for (int f = 0; f < 2; ++f)
#pragma unroll
    for (int ct = 0; ct < 4; ++ct)
#pragma unroll
      for (int i = 0; i < 4; ++i) acc[f][ct][i] = 0.f;

  auto loadA = [&](int t, int s) {
    Ab[s][0][0] = *(const f32x4*)(pA0 + t * BKC);
    Ab[s][0][1] = *(const f32x4*)(pA0 + t * BKC + 4);
    Ab[s][1][0] = *(const f32x4*)(pA1 + t * BKC);
    Ab[s][1][1] = *(const f32x4*)(pA1 + t * BKC + 4);
  };
  auto loadB = [&](int t, int s) {
    const short* p = pB + (size_t)t * 4096;
#pragma unroll
    for (int ct = 0; ct < 4; ++ct) {
      Bh[s][ct] = *(const short8*)(p + ct * 1024);
      Bl[s][ct] = *(const short8*)(p + ct * 1024 + 32);
    }
  };

  // HW packed f32->bf16 split: hi = rne(x,y), lo = rne(residual)
  auto cvtpk = [&](float x, float y, unsigned& hw, unsigned& lw) {
    union { __hip_bfloat162 b; unsigned u; } Hh, Ll;
    Hh.b = __float22bfloat162_rn(float2{x, y});
    float2 hf = __bfloat1622float2(Hh.b);
    Ll.b = __float22bfloat162_rn(float2{x - hf.x, y - hf.y});
    hw = Hh.u; lw = Ll.u;
  };

  // prologue: A(0..3) depth-4, B(0) depth-1
  loadA(0, 0);
  loadB(0, 0);
  loadA(1, 1);
  loadA(2, 2);
  loadA(3, 3);

#pragma unroll
  for (int t = 0; t < CPW; ++t) {
    const int d = t & 3, p = t & 1;
    // B(t+1) first (opposite slot, no WAR; 1-body slack before use)
    if (t + 1 < CPW) loadB(t + 1, (t + 1) & 1);
    // convert A(t) to hi/lo bf16 fragments
    union { short8 v; unsigned u[4]; } AH0, AL0, AH1, AL1;
    cvtpk(Ab[d][0][0][0], Ab[d][0][0][1], AH0.u[0], AL0.u[0]);
    cvtpk(Ab[d][0][0][2], Ab[d][0][0][3], AH0.u[1], AL0.u[1]);
    cvtpk(Ab[d][0][1][0], Ab[d][0][1][1], AH0.u[2], AL0.u[2]);
    cvtpk(Ab[d][0][1][2], Ab[d][0][1][3], AH0.u[3], AL0.u[3]);
    cvtpk(Ab[d][1][0][0], Ab[d][1][0][1], AH1.u[0], AL1.u[0]);
    cvtpk(Ab[d][1][0][2], Ab[d][1][0][3], AH1.u[1], AL1.u[1]);
    cvtpk(Ab[d][1][1][0], Ab[d][1][1][1], AH1.u[2], AL1.u[2]);
    cvtpk(Ab[d][1][1][2], Ab[d][1][1][3], AH1.u[3], AL1.u[3]);
    // A(t+4) into the slot just consumed (issued early; 3-body slack)
    if (t + 4 < CPW) loadA(t + 4, d);
    // 24 MFMA: 2 frags x 4 ct x 3 split-terms
#pragma unroll
    for (int ct = 0; ct < 4; ++ct) {
      acc[0][ct] = __builtin_amdgcn_mfma_f32_16x16x32_bf16(AH0.v, Bh[p][ct], acc[0][ct], 0, 0, 0);
      acc[0][ct] = __builtin_amdgcn_mfma_f32_16x16x32_bf16(AL0.v, Bh[p][ct], acc[0][ct], 0, 0, 0);
      acc[0][ct] = __builtin_amdgcn_mfma_f32_16x16x32_bf16(AH0.v, Bl[p][ct], acc[0][ct], 0, 0, 0);
      acc[1][ct] = __builtin_amdgcn_mfma_f32_16x16x32_bf16(AH1.v, Bh[p][ct], acc[1][ct], 0, 0, 0);
      acc[1][ct] = __builtin_amdgcn_mfma_f32_16x16x32_bf16(AL1.v, Bh[p][ct], acc[1][ct], 0, 0, 0);
      acc[1][ct] = __builtin_amdgcn_mfma_f32_16x16x32_bf16(AH1.v, Bl[p][ct], acc[1][ct], 0, 0, 0);
    }
  }

  // --- store K-partials: D layout col = lane&15, row = 4q+rr (within frag) ---
#pragma unroll
  for (int f = 0; f < 2; ++f)
#pragma unroll
    for (int ct = 0; ct < 4; ++ct)
#pragma unroll
      for (int rr = 0; rr < 4; ++rr)
        part[w][16 * f + 4 * q + rr][16 * ct + r] = acc[f][ct][rr];
  __syncthreads();

  // --- reduce 4 K-quarters: thread tid owns 8 outputs (row tid>>3, cols 8) ---
  {
    const int row = tid >> 3, col = (tid & 7) * 8;
    f32x4 s0 = *(const f32x4*)&part[0][row][col];
    f32x4 s1 = *(const f32x4*)&part[0][row][col + 4];
#pragma unroll
    for (int ww = 1; ww < 4; ++ww) {
      s0 += *(const f32x4*)&part[ww][row][col];
      s1 += *(const f32x4*)&part[ww][row][col + 4];
    }
    *(f32x4*)&logits[(size_t)(row0 + row) * E + col]     = s0;
    *(f32x4*)&logits[(size_t)(row0 + row) * E + col + 4] = s1;
    *(f32x4*)&part[0][row][col]     = s0;   // own slice only — race-free
    *(f32x4*)&part[0][row][col + 4] = s1;
  }
  __syncthreads();

  // --- fused top-2 + renorm: threads 0..31, one row each, staggered scan ---
  if (tid < 32) {
    const float* rowp = &part[0][tid][0];
    float bv = -3.4e38f; int bi = 1 << 30;
#pragma unroll 8
    for (int e0 = 0; e0 < E; ++e0) {
      const int e = (e0 + tid) & 63;   // stagger: conflict-free banks
      const float v = rowp[e];
      if (v > bv || (v == bv && e < bi)) { bv = v; bi = e; }
    }
    float sv = -3.4e38f; int si = 1 << 30;
#pragma unroll 8
    for (int e0 = 0; e0 < E; ++e0) {
      const int e = (e0 + tid) & 63;
      const float v = rowp[e];
      if (e != bi && (v > sv || (v == sv && e < si))) { sv = v; si = e; }
    }
    // w1 = p1/(p1+p2) = 1/(1+e^{x2-x1}); softmax denominator cancels
    const float w1 = 1.0f / (1.0f + __expf(sv - bv));
    const int R = row0 + tid;
    topw[(size_t)R * 2 + 0] = w1;
    topw[(size_t)R * 2 + 1] = 1.0f - w1;
    topi[(size_t)R * 2 + 0] = (float)bi;
    topi[(size_t)R * 2 + 1] = (float)si;
  }
}

extern "C" void kernel_launch(void* const* d_in, const int* in_sizes, int n_in,
                              void* d_out, int out_size, void* d_ws, size_t ws_size,
                              hipStream_t stream) {
  const float* H = (const float*)d_in[0];  // [16384, 4096] fp32
  const float* W = (const float*)d_in[1];  // [64, 4096] fp32

  float* out    = (float*)d_out;
  float* topw   = out;                       // [16384, 2]
  float* logits = out + (size_t)T * 2;       // [16384, 64]
  float* topi   = logits + (size_t)T * E;    // [16384, 2] (indices as float)

  short* wimg = (short*)d_ws;                // 1 MiB packed W image

  wprep<<<256, 256, 0, stream>>>(W, wimg);
  router_fused<<<T / 32, 256, 0, stream>>>(H, wimg, logits, topw, topi);
}